// Round 11
// baseline (529.257 us; speedup 1.0000x reference)
//
#include <hip/hip_runtime.h>
#include <hip/hip_bf16.h>
#include <stdint.h>

// Problem constants (fixed by the reference)
#define HD      4096            // K (hidden)
#define MROWS   8192            // B*S
#define NQ      4096
#define NKV     1024
#define NTOT    6144            // NQ + 2*NKV
#define RMS_EPS 1e-6f

typedef __attribute__((ext_vector_type(8))) short bf16x8;
typedef __attribute__((ext_vector_type(16))) float f32x16;

static __device__ __forceinline__ unsigned short f2bf(float f) {
  union { float f; unsigned u; } a; a.f = f;
  unsigned r = a.u + 0x7FFFu + ((a.u >> 16) & 1u);   // RNE
  return (unsigned short)(r >> 16);
}

// ------- Fused prep: rmsnorm (blocks 0..8191) + 3 transposes (8192..32767) ---
__global__ __launch_bounds__(256) void prep_kernel(
    const float* __restrict__ x, const float* __restrict__ gamma,
    const float* __restrict__ wq, const float* __restrict__ wk,
    const float* __restrict__ wv,
    unsigned short* __restrict__ xn, unsigned short* __restrict__ wt) {
  __shared__ float smem[32 * 33];
  const int bid = blockIdx.x;
  const int t = threadIdx.x;
  if (bid < MROWS) {
    const float4* xr = (const float4*)(x + (size_t)bid * HD);
    const float4* g4 = (const float4*)gamma;
    float4 v[4];
    float ss = 0.f;
#pragma unroll
    for (int i = 0; i < 4; ++i) {
      v[i] = xr[t + i * 256];
      ss += v[i].x * v[i].x + v[i].y * v[i].y + v[i].z * v[i].z + v[i].w * v[i].w;
    }
#pragma unroll
    for (int o = 32; o > 0; o >>= 1) ss += __shfl_xor(ss, o, 64);
    if ((t & 63) == 0) smem[t >> 6] = ss;
    __syncthreads();
    const float tot = smem[0] + smem[1] + smem[2] + smem[3];
    const float rstd = rsqrtf(tot * (1.f / HD) + RMS_EPS);
    ushort4* xo = (ushort4*)(xn + (size_t)bid * HD);
#pragma unroll
    for (int i = 0; i < 4; ++i) {
      const float4 g = g4[t + i * 256];
      ushort4 o;
      o.x = f2bf(v[i].x * rstd * g.x);
      o.y = f2bf(v[i].y * rstd * g.y);
      o.z = f2bf(v[i].z * rstd * g.z);
      o.w = f2bf(v[i].w * rstd * g.w);
      xo[t + i * 256] = o;
    }
  } else {
    int b2 = bid - MROWS;
    const float* w; unsigned short* dst; int Nw, nb, kt;
    if (b2 < 16384)      { w = wq; dst = wt;                           Nw = NQ;  nb = b2 & 127; kt = b2 >> 7; }
    else if (b2 < 20480) { b2 -= 16384; w = wk; dst = wt + (size_t)NQ * HD;         Nw = NKV; nb = b2 & 31; kt = b2 >> 5; }
    else                 { b2 -= 20480; w = wv; dst = wt + (size_t)(NQ + NKV) * HD; Nw = NKV; nb = b2 & 31; kt = b2 >> 5; }
    const int r = t >> 3, c4 = t & 7;
    const float4 vin = *(const float4*)&w[(size_t)(kt * 32 + r) * Nw + nb * 32 + c4 * 4];
    smem[r * 33 + c4 * 4 + 0] = vin.x;
    smem[r * 33 + c4 * 4 + 1] = vin.y;
    smem[r * 33 + c4 * 4 + 2] = vin.z;
    smem[r * 33 + c4 * 4 + 3] = vin.w;
    __syncthreads();
    ushort4 o;
    o.x = f2bf(smem[(c4 * 4 + 0) * 33 + r]);
    o.y = f2bf(smem[(c4 * 4 + 1) * 33 + r]);
    o.z = f2bf(smem[(c4 * 4 + 2) * 33 + r]);
    o.w = f2bf(smem[(c4 * 4 + 3) * 33 + r]);
    *(ushort4*)&dst[(size_t)(nb * 32 + r) * HD + kt * 32 + c4 * 4] = o;
  }
}

// ---- 256x256 4-wave (1 wave/SIMD) bf16 GEMM, 32x32x16, k-chunked LDS --------
// C[M,N] = A[M,K] * Bt[N,K]^T ; M=8192, N=6144, K=4096. BK=64, 256 thr.
//
// Rationale: with 2 waves/SIMD, LDS reads (0.0234 B/FLOP) exceed the MFMA
// pipe; 4 waves x 128x128-per-wave (acc 256 regs, 1 wave/SIMD) halves the
// read redundancy (0.0156 B/FLOP): reads 1536 cyc < MFMA 2066 cyc per K-tile.
//
// LDS: lds[mat][buf][ks-chunk 0-3][256 rows x 16 elem(32B)] (8KB chunks).
// Read addr (row, hi): ks-chunk base + row*32 + hi*16 ^ (((row>>2)&7)<<4)
//   -> per 16-lane quarter: 8 slots x 2 lanes (2-way = free).
// Stage: linear dest (wave w covers rows via inverse-swizzle decode of
//   p = w*1024 + lane*16 (+pass*4096)); source = row(p)*HD + hi(p)*8 + koff.
//
// Uniform phase = [8 ds_read (set for NEXT ks) ; 4 gload_lds (A+B chunk) ;
//                  16 MFMA (current set) ; VM20 ; BAR]
// Per tile T (buf b = T&1, nb = !b); sets ping-pong s0/s1:
//   p0: MFMA s0(ks0), read s1<-(b,ks1),  stage c3(T+1)->nb @ (T+1)*64+48
//   p1: MFMA s1(ks1), read s0<-(b,ks2),  stage c0(T+2)->b  @ (T+2)*64
//   p2: MFMA s0(ks2), read s1<-(b,ks3),  stage c1(T+2)->b  @ +16
//   p3: MFMA s1(ks3), read s0<-(nb,ks0), stage c2(T+2)->b  @ +32
// Ledger (per-wave, 4 gloads/phase, FIFO):
//   Landing: chunk staged at phase X first read at X+6; VM20 at end of X+5
//     retires it (outstanding 24 -> 20). Uniform, never vmcnt(0) in loop.
//   Overwrite: chunk staged at X overwrites data last read at X-2, whose
//     lgkm retired before MFMA(X-1) + BAR(X-1) -> safe.
//   Prologue: 28 gloads (t0 c0-3, t1 c0-2, A then B per chunk); VM20 retires
//     {t0 Ac0,Bc0,Ac1,Bc1} -> pre-read ks0 and T0.p0's ks1 reads safe; the
//     in-loop VM20 cadence then retires exactly the just-in-time chunk
//     (verified T0.p0..T1.p3 by FIFO simulation).
//   Tail: stage k-offsets clamped to tile 63 (schedule slots unchanged ->
//     same bufs, safe); T63.p3's reads are dead; VM0 after loop.

static __device__ __forceinline__ void gload_lds16(const unsigned short* g,
                                                   unsigned short* l) {
  __builtin_amdgcn_global_load_lds(
      (const __attribute__((address_space(1))) void*)g,
      (__attribute__((address_space(3))) void*)l, 16, 0, 0);
}

#define VM20 asm volatile("s_waitcnt vmcnt(20)" ::: "memory")
#define VM0  asm volatile("s_waitcnt vmcnt(0)" ::: "memory")
#define BARR __builtin_amdgcn_s_barrier()

// read one set: 4 A frags (mi) + 4 B frags (j) from (BUF, KS) bases
#define RD(AN, BN, BUF, KS)                                                    \
  do {                                                                         \
    _Pragma("unroll") for (int mi = 0; mi < 4; ++mi)                           \
      AN[mi] = *(const bf16x8*)(ab[BUF][KS] + mi * 1024);                      \
    _Pragma("unroll") for (int j = 0; j < 4; ++j)                              \
      BN[j] = *(const bf16x8*)(bb2[BUF][KS] + j * 1024);                       \
  } while (0)

// 16 MFMA with set (AN, BN); all 16 acc blocks independent (no RAW chain)
#define MMA(AN, BN)                                                            \
  do {                                                                         \
    _Pragma("unroll") for (int mi = 0; mi < 4; ++mi)                           \
      _Pragma("unroll") for (int j = 0; j < 4; ++j)                            \
        acc[mi][j] = __builtin_amdgcn_mfma_f32_32x32x16_bf16(                  \
            AN[mi], BN[j], acc[mi][j], 0, 0, 0);                               \
  } while (0)

// stage one 8KB chunk of mat M into lds[M][BUF][C]: 2 gloads (rows 0-127/128-255)
#define STGA(BUF, C, KOFF)                                                     \
  do {                                                                         \
    gload_lds16(Ab + so0 + (KOFF), &lds[0][BUF][C][0] + w * 512);              \
    gload_lds16(Ab + so1 + (KOFF), &lds[0][BUF][C][0] + 2048 + w * 512);       \
  } while (0)
#define STGB(BUF, C, KOFF)                                                     \
  do {                                                                         \
    gload_lds16(Bb + so0 + (KOFF), &lds[1][BUF][C][0] + w * 512);              \
    gload_lds16(Bb + so1 + (KOFF), &lds[1][BUF][C][0] + 2048 + w * 512);       \
  } while (0)

#define TILE(B, NB, KO1, KO2)                                                  \
  do {                                                                         \
    RD(s1a, s1b, B, 1); STGA(NB, 3, (KO1) + 48); STGB(NB, 3, (KO1) + 48);      \
    MMA(s0a, s0b); VM20; BARR;                                                 \
    RD(s0a, s0b, B, 2); STGA(B, 0, (KO2));      STGB(B, 0, (KO2));             \
    MMA(s1a, s1b); VM20; BARR;                                                 \
    RD(s1a, s1b, B, 3); STGA(B, 1, (KO2) + 16); STGB(B, 1, (KO2) + 16);        \
    MMA(s0a, s0b); VM20; BARR;                                                 \
    RD(s0a, s0b, NB, 0); STGA(B, 2, (KO2) + 32); STGB(B, 2, (KO2) + 32);       \
    MMA(s1a, s1b); VM20; BARR;                                                 \
  } while (0)

__global__ __launch_bounds__(256, 1) void gemm_qkv_kernel(
    const unsigned short* __restrict__ A,    // [MROWS][HD] bf16 (xn)
    const unsigned short* __restrict__ Bt,   // [NTOT][HD] bf16 (w^T)
    float* __restrict__ out) {
  // [mat][buf][ks-chunk][256 rows x 16 elem] bf16 = 128 KiB
  __shared__ unsigned short lds[2][2][4][4096] __attribute__((aligned(16)));

  // XCD-rectangular swizzle: grid 32mt x 24nt = 768 blocks, XCD = bid&7.
  const int bid = blockIdx.x;
  const int xcd = bid & 7;
  const int idx = bid >> 3;                  // 0..95
  const int sr  = idx >> 5;                  // sub-round 0..2
  const int i32 = idx & 31;
  const int mt  = (xcd >> 1) * 8 + (i32 >> 2);
  const int nt  = (xcd & 1) * 12 + sr * 4 + (i32 & 3);
  const int m0 = mt * 256, n0 = nt * 256;

  const int tid = threadIdx.x;
  const int w = tid >> 6, lane = tid & 63;   // 4 waves
  const int wr = w >> 1, wc = w & 1;         // 2x2 wave grid, each 128x128 out
  const int r32 = lane & 31, hi = lane >> 5;
  const int swz = ((r32 >> 2) & 7) << 4;

  // 16 loop-invariant read base pointers (row + swizzle folded in)
  const char* ab[2][4]; const char* bb2[2][4];
#pragma unroll
  for (int buf = 0; buf < 2; ++buf)
#pragma unroll
    for (int ks = 0; ks < 4; ++ks) {
      ab[buf][ks]  = (const char*)&lds[0][buf][ks][0] +
                     ((((wr * 128 + r32) * 32 + hi * 16)) ^ swz);
      bb2[buf][ks] = (const char*)&lds[1][buf][ks][0] +
                     ((((wc * 128 + r32) * 32 + hi * 16)) ^ swz);
    }

  // staging source decode: physical LDS byte p = w*1024 + lane*16 (+pass*4096)
  // maps (post-read-swizzle) to content (row, hi): r0=(l>>1^l>>4)&1,
  // r1=(l>>2^l>>5)&1, hi=(l^l>>3)&1, row = r0+2*r1+4*((l>>3)&7)+32*w(+128*pass)
  const int sr0 = ((lane >> 1) ^ (lane >> 4)) & 1;
  const int sr1 = ((lane >> 2) ^ (lane >> 5)) & 1;
  const int shi = (lane ^ (lane >> 3)) & 1;
  const int srow = sr0 + 2 * sr1 + 4 * ((lane >> 3) & 7) + 32 * w;
  const unsigned so0 = (unsigned)srow * HD + shi * 8;
  const unsigned so1 = so0 + 128u * HD;

  const unsigned short* const Ab = A + (size_t)m0 * HD;
  const unsigned short* const Bb = Bt + (size_t)n0 * HD;

  f32x16 acc[4][4];
#pragma unroll
  for (int i = 0; i < 4; ++i)
#pragma unroll
    for (int j = 0; j < 4; ++j) acc[i][j] = (f32x16)(0.f);

  bf16x8 s0a[4], s0b[4], s1a[4], s1b[4];     // ping-pong operand sets

  // prologue: t0 chunks c0-3, t1 chunks c0-2 (A then B per chunk) = 28 gloads
#pragma unroll
  for (int c = 0; c < 4; ++c) { STGA(0, c, c * 16); STGB(0, c, c * 16); }
#pragma unroll
  for (int c = 0; c < 3; ++c) { STGA(1, c, 64 + c * 16); STGB(1, c, 64 + c * 16); }
  VM20;                                      // retires t0 Ac0,Bc0,Ac1,Bc1
  BARR;
  RD(s0a, s0b, 0, 0);                        // tile0 ks0

  for (int t = 0; t < 32; ++t) {
    const int u1 = 2 * t + 1, u2 = 2 * t + 2, u3 = 2 * t + 3;
    const int ko1 = (u1 < 64 ? u1 : 63) * 64;
    const int ko2 = (u2 < 64 ? u2 : 63) * 64;
    const int ko3 = (u3 < 64 ? u3 : 63) * 64;
    TILE(0, 1, ko1, ko2);                    // tile 2t   (buf0)
    TILE(1, 0, ko2, ko3);                    // tile 2t+1 (buf1)
  }
  VM0;                                       // drain trailing clamped stages

  // epilogue: route this block's 256 columns to q / k / v region
  size_t obase; int ldc, nc;
  if (n0 < NQ)            { obase = 0;                                        ldc = NQ;  nc = n0; }
  else if (n0 < NQ + NKV) { obase = (size_t)MROWS * NQ;                       ldc = NKV; nc = n0 - NQ; }
  else                    { obase = (size_t)MROWS * NQ + (size_t)MROWS * NKV; ldc = NKV; nc = n0 - NQ - NKV; }

  // C/D layout (verified m74/m101): col = lane&31, row = (reg&3)+8*(reg>>2)+4*hi
#pragma unroll
  for (int mi = 0; mi < 4; ++mi) {
    const int rbase = m0 + wr * 128 + mi * 32 + hi * 4;
#pragma unroll
    for (int j = 0; j < 4; ++j) {
      const int col = nc + wc * 128 + j * 32 + r32;
#pragma unroll
      for (int reg = 0; reg < 16; ++reg) {
        const int row = rbase + (reg & 3) + 8 * (reg >> 2);
        out[obase + (size_t)row * ldc + col] = acc[mi][j][reg];
      }
    }
  }
}

extern "C" void kernel_launch(void* const* d_in, const int* in_sizes, int n_in,
                              void* d_out, int out_size, void* d_ws, size_t ws_size,
                              hipStream_t stream) {
  const float* x     = (const float*)d_in[0];
  const float* gamma = (const float*)d_in[1];
  const float* wq    = (const float*)d_in[2];
  const float* wk    = (const float*)d_in[3];
  const float* wv    = (const float*)d_in[4];
  float* out = (float*)d_out;

  // workspace layout: xn bf16 [8192][4096] then wt bf16 [6144][4096]
  unsigned short* xn = (unsigned short*)d_ws;
  unsigned short* wt = xn + (size_t)MROWS * HD;

  prep_kernel<<<32768, 256, 0, stream>>>(x, gamma, wq, wk, wv, xn, wt);
  gemm_qkv_kernel<<<(MROWS / 256) * (NTOT / 256), 256, 0, stream>>>(xn, wt, out);
}